// Round 5
// baseline (92.553 us; speedup 1.0000x reference)
//
#include <hip/hip_runtime.h>
#include <hip/hip_fp16.h>

// Flash-attention: B=16, Lq=Lk=2048, D=128, fp32 in/out, per-batch key masking.
// R5: pre-pass converts K->f16 Kh[b][k][d] and V->f16 transposed Vt[b][d][k] in d_ws
// (halves L2 staging bytes; removes in-loop cvt+scatter). Batch scramble
// b=(blk^blk>>4)&15 balances XCDs. P tile [16][64] with 16B XOR swizzle (conflict-free,
// 16B-aligned). LDS 40KB -> 3 blocks/CU residency.

typedef _Float16 f16x2 __attribute__((ext_vector_type(2)));
typedef _Float16 f16x4 __attribute__((ext_vector_type(4)));
typedef _Float16 f16x8 __attribute__((ext_vector_type(8)));
typedef __fp16   n16x2 __attribute__((ext_vector_type(2)));
typedef float    f32x4 __attribute__((ext_vector_type(4)));

#define LQ 2048
#define LK 2048
#define DIM 128
#define KT 64          // keys per tile
#define NW 4           // waves per block
#define QW 16          // q-rows per wave

__device__ __forceinline__ f16x2 cvt2(float a, float b) {
    n16x2 t = __builtin_amdgcn_cvt_pkrtz(a, b);
    return __builtin_bit_cast(f16x2, t);
}

__device__ __forceinline__ f16x8 pk8(float4 a, float4 b) {
    f16x2 p0 = cvt2(a.x, a.y), p1 = cvt2(a.z, a.w);
    f16x2 p2 = cvt2(b.x, b.y), p3 = cvt2(b.z, b.w);
    f16x8 r;
    r[0]=p0[0]; r[1]=p0[1]; r[2]=p1[0]; r[3]=p1[1];
    r[4]=p2[0]; r[5]=p2[1]; r[6]=p3[0]; r[7]=p3[1];
    return r;
}

__device__ __forceinline__ float fel(const float4& a, const float4& b, int d) {
    const float arr[8] = {a.x,a.y,a.z,a.w,b.x,b.y,b.z,b.w};
    return arr[d];
}

// V^T LDS byte offset: d rows (128B each), key cols; 16B-block XOR swizzle
__device__ __forceinline__ int vt_off(int d, int k) {
    return d*128 + (((k >> 3) ^ ((d ^ (d >> 3)) & 7)) << 4) + (k & 7) * 2;
}

// ---------------- pre-pass A: K fp32 -> f16 (same layout) ----------------
__global__ __launch_bounds__(256)
void cvtK_kernel(const float* __restrict__ K, _Float16* __restrict__ Kh) {
    size_t idx = ((size_t)blockIdx.x * 256 + threadIdx.x) * 8;
    float4 a = *(const float4*)(K + idx);
    float4 b = *(const float4*)(K + idx + 4);
    *(f16x8*)(Kh + idx) = pk8(a, b);
}

// ---------------- pre-pass B: V fp32 [b][k][d] -> f16 Vt [b][d][k] ----------------
__global__ __launch_bounds__(256)
void cvtV_kernel(const float* __restrict__ V, _Float16* __restrict__ Vt) {
    __shared__ _Float16 t[64 * 136];   // 64 keys x 128 d, stride 136 (column-gather friendly)
    const int blk = blockIdx.x, tid = threadIdx.x;
    const int b = blk >> 5, kt = blk & 31, k0 = kt * 64;
    const float* src = V + ((size_t)b * LK + k0) * DIM;
    #pragma unroll
    for (int i = 0; i < 4; ++i) {
        int e = i * 2048 + tid * 8;
        int row = e >> 7, d = e & 127;
        float4 a = *(const float4*)(src + row * DIM + d);
        float4 c = *(const float4*)(src + row * DIM + d + 4);
        *(f16x8*)(&t[row * 136 + d]) = pk8(a, c);
    }
    __syncthreads();
    const int d = tid >> 1, kh = (tid & 1) * 32;
    _Float16* dst = Vt + ((size_t)b * DIM + d) * LK + k0 + kh;
    #pragma unroll
    for (int c = 0; c < 4; ++c) {
        f16x8 w;
        #pragma unroll
        for (int j = 0; j < 8; ++j) w[j] = t[(kh + c * 8 + j) * 136 + d];
        *(f16x8*)(dst + c * 8) = w;
    }
}

// ---------------- main flash-attention kernel ----------------
template<bool PRE>
__global__ __launch_bounds__(256, 3)
void fa_kernel(const float* __restrict__ Qg, const float* __restrict__ Kg,
               const float* __restrict__ Vg, const _Float16* __restrict__ Kh,
               const _Float16* __restrict__ Vt, const int* __restrict__ VLg,
               float* __restrict__ Og)
{
    __shared__ __align__(16) _Float16 ldsK[KT * DIM];     // 16 KB, XOR-swizzled rows
    __shared__ __align__(16) _Float16 ldsVT[DIM * KT];    // 16 KB, vt_off layout
    __shared__ __align__(16) _Float16 ldsP[NW][16 * 64];  // 8 KB, XOR-swizzled rows

    const int tid = threadIdx.x, wv = tid >> 6, lane = tid & 63;
    const int lg = lane >> 4, ln = lane & 15;
    const int blk = blockIdx.x, qt = blk >> 4;
    const int b = (blk ^ qt) & 15;                 // bijective batch scramble (XCD balance)
    const int q0 = qt * (NW * QW) + wv * QW;
    const int nvalid = VLg[b];                     // 1..2048
    const int nt = (nvalid + KT - 1) / KT;         // skip fully-masked tiles (exact)
    const float SCL = 0.08838834764831845f * 1.44269504088896341f; // 1/sqrt(128)*log2e

    const float*    Kb32 = Kg + (size_t)b * LK * DIM;
    const float*    Vb32 = Vg + (size_t)b * LK * DIM;
    const _Float16* Kb16 = Kh + (size_t)b * LK * DIM;
    const _Float16* Vtb  = Vt + (size_t)b * DIM * LK;

    // Q fragments (B-operand of swapped QK, pre-scaled)
    f16x8 qf[4];
    {
        const float* qr = Qg + ((size_t)b*LQ + q0 + ln)*DIM + lg*8;
        #pragma unroll
        for (int dc = 0; dc < 4; ++dc) {
            float4 a = *(const float4*)(qr + dc*32);
            float4 c = *(const float4*)(qr + dc*32 + 4);
            a.x*=SCL; a.y*=SCL; a.z*=SCL; a.w*=SCL;
            c.x*=SCL; c.y*=SCL; c.z*=SCL; c.w*=SCL;
            qf[dc] = pk8(a, c);
        }
    }

    // staging registers (only the active set is live after DCE)
    f16x8 rk[4], rv[4];
    float4 ka[4], kb4[4], va[4], vb[4];

    auto issue = [&](int k0) {
        if constexpr (PRE) {
            #pragma unroll
            for (int i = 0; i < 4; ++i) {
                int c = tid + i*256;
                rk[i] = *(const f16x8*)(Kb16 + (size_t)(k0 + (c>>4))*DIM + (c&15)*8);
            }
            #pragma unroll
            for (int i = 0; i < 4; ++i) {
                int c = tid + i*256;
                rv[i] = *(const f16x8*)(Vtb + (size_t)(c>>3)*LK + k0 + (c&7)*8);
            }
        } else {
            #pragma unroll
            for (int i = 0; i < 4; ++i) {
                int c = tid + i*256, row = c >> 4, d0 = (c & 15) * 8;
                const float* s = Kb32 + (size_t)(k0 + row)*DIM + d0;
                ka[i] = *(const float4*)s;  kb4[i] = *(const float4*)(s+4);
            }
            int kq = tid >> 4, d0 = (tid & 15) * 8;
            #pragma unroll
            for (int j = 0; j < 4; ++j) {
                const float* s = Vb32 + (size_t)(k0 + kq*4 + j)*DIM + d0;
                va[j] = *(const float4*)s;  vb[j] = *(const float4*)(s+4);
            }
        }
    };

    auto swrite = [&]() {
        char* kbase = (char*)ldsK;
        char* vbase = (char*)ldsVT;
        if constexpr (PRE) {
            #pragma unroll
            for (int i = 0; i < 4; ++i) {
                int c = tid + i*256, row = c >> 4, d0 = (c & 15) * 8;
                *(f16x8*)(kbase + (((row << 8) + (d0 << 1)) ^ ((row & 7) << 4))) = rk[i];
            }
            #pragma unroll
            for (int i = 0; i < 4; ++i) {
                int c = tid + i*256, d = c >> 3, bb = c & 7;
                *(f16x8*)(vbase + d*128 + ((bb ^ ((d ^ (d >> 3)) & 7)) << 4)) = rv[i];
            }
        } else {
            #pragma unroll
            for (int i = 0; i < 4; ++i) {
                int c = tid + i*256, row = c >> 4, d0 = (c & 15) * 8;
                *(f16x8*)(kbase + (((row << 8) + (d0 << 1)) ^ ((row & 7) << 4))) = pk8(ka[i], kb4[i]);
            }
            int kq = tid >> 4, d0 = (tid & 15) * 8;
            #pragma unroll
            for (int dd = 0; dd < 8; ++dd) {
                f16x2 lo = cvt2(fel(va[0],vb[0],dd), fel(va[1],vb[1],dd));
                f16x2 hi = cvt2(fel(va[2],vb[2],dd), fel(va[3],vb[3],dd));
                f16x4 w; w[0]=lo[0]; w[1]=lo[1]; w[2]=hi[0]; w[3]=hi[1];
                *(f16x4*)(vbase + vt_off(d0 + dd, 4*kq)) = w;
            }
        }
    };

    issue(0);
    swrite();
    __syncthreads();

    f32x4 acc[8];
    #pragma unroll
    for (int t = 0; t < 8; ++t) acc[t] = (f32x4){0.f,0.f,0.f,0.f};
    float mrow = -__builtin_inff();
    float lrow = 0.f;

    char* pbase = (char*)&ldsP[wv][0];
    char* kbase = (char*)ldsK;
    char* vbase = (char*)ldsVT;

    for (int t = 0; t < nt; ++t) {
        const int k0 = t * KT;
        const bool more = (t + 1 < nt);
        if (more) issue(k0 + KT);   // T14: loads in flight across compute

        // ---- swapped QK^T: s = mfma(K_chunk, Q) -> D[key][q], q = ln lane-local ----
        f32x4 s[4];
        #pragma unroll
        for (int kc = 0; kc < 4; ++kc) s[kc] = (f32x4){0.f,0.f,0.f,0.f};
        __builtin_amdgcn_s_setprio(1);
        #pragma unroll
        for (int kc = 0; kc < 4; ++kc) {
            #pragma unroll
            for (int dc = 0; dc < 4; ++dc) {
                f16x8 kf = *(const f16x8*)(kbase +
                    ((((kc*16 + ln) << 8) + dc*64 + lg*16) ^ ((ln & 7) << 4)));
                s[kc] = __builtin_amdgcn_mfma_f32_16x16x32_f16(kf, qf[dc], s[kc], 0,0,0);
            }
        }
        __builtin_amdgcn_s_setprio(0);

        // ---- boundary mask (last tile only): key index = k0 + kc*16 + 4*lg + r ----
        if (k0 + KT > nvalid) {
            #pragma unroll
            for (int kc = 0; kc < 4; ++kc)
                #pragma unroll
                for (int r = 0; r < 4; ++r)
                    if (k0 + kc*16 + 4*lg + r >= nvalid) s[kc][r] = -1e30f;
        }

        // ---- online softmax (q-row = ln, lane-local) ----
        float pm = s[0][0];
        #pragma unroll
        for (int kc = 0; kc < 4; ++kc)
            #pragma unroll
            for (int r = 0; r < 4; ++r) pm = fmaxf(pm, s[kc][r]);
        pm = fmaxf(pm, __shfl_xor(pm, 16));
        pm = fmaxf(pm, __shfl_xor(pm, 32));

        if (__any(pm > mrow)) {            // T13: skip rescale when max didn't grow
            float mn   = fmaxf(mrow, pm);
            float corr = __builtin_amdgcn_exp2f(mrow - mn);
            mrow = mn;
            lrow *= corr;
            float cr0 = __shfl(corr, 4*lg+0), cr1 = __shfl(corr, 4*lg+1);
            float cr2 = __shfl(corr, 4*lg+2), cr3 = __shfl(corr, 4*lg+3);
            #pragma unroll
            for (int tt = 0; tt < 8; ++tt) {
                acc[tt][0]*=cr0; acc[tt][1]*=cr1;
                acc[tt][2]*=cr2; acc[tt][3]*=cr3;
            }
        }

        float rs = 0.f;
        #pragma unroll
        for (int kc = 0; kc < 4; ++kc) {
            float p0 = __builtin_amdgcn_exp2f(s[kc][0] - mrow);  // masked -> exact 0
            float p1 = __builtin_amdgcn_exp2f(s[kc][1] - mrow);
            float p2 = __builtin_amdgcn_exp2f(s[kc][2] - mrow);
            float p3 = __builtin_amdgcn_exp2f(s[kc][3] - mrow);
            rs += (p0 + p1) + (p2 + p3);
            f16x2 lo = cvt2(p0, p1);
            f16x2 hi = cvt2(p2, p3);
            f16x4 w; w[0]=lo[0]; w[1]=lo[1]; w[2]=hi[0]; w[3]=hi[1];
            // P[q=ln][k], stride 128B, 16B-granule XOR swizzle (write 8B, no straddle)
            *(f16x4*)(pbase + (ln << 7) + ((kc*32 + lg*8) ^ ((ln & 7) << 4))) = w;
        }
        rs += __shfl_xor(rs, 16);
        rs += __shfl_xor(rs, 32);
        lrow += rs;

        asm volatile("s_waitcnt lgkmcnt(0)" ::: "memory");  // P writes -> af reads (same wave)

        // ---- PV: acc[tt] += P (A) x V (B) ----
        f16x8 af[2];
        #pragma unroll
        for (int kc2 = 0; kc2 < 2; ++kc2)
            af[kc2] = *(const f16x8*)(pbase + (ln << 7) + ((kc2*64 + lg*16) ^ ((ln & 7) << 4)));
        __builtin_amdgcn_s_setprio(1);
        #pragma unroll
        for (int tt = 0; tt < 8; ++tt) {
            #pragma unroll
            for (int kc2 = 0; kc2 < 2; ++kc2) {
                f16x8 bf = *(const f16x8*)(vbase + vt_off(tt*16 + ln, kc2*32 + lg*8));
                acc[tt] = __builtin_amdgcn_mfma_f32_16x16x32_f16(af[kc2], bf, acc[tt], 0,0,0);
            }
        }
        __builtin_amdgcn_s_setprio(0);

        if (more) {
            __syncthreads();     // all waves done reading tile t
            swrite();            // vmcnt waits auto-inserted
            __syncthreads();     // tile t+1 visible
        }
    }

    // ---- epilogue: O = acc / l ----
    {
        float linv = 1.f / lrow;
        float l0 = __shfl(linv, 4*lg+0), l1 = __shfl(linv, 4*lg+1);
        float l2 = __shfl(linv, 4*lg+2), l3 = __shfl(linv, 4*lg+3);
        const float lr[4] = {l0, l1, l2, l3};
        #pragma unroll
        for (int r = 0; r < 4; ++r) {
            float* orow = Og + ((size_t)b*LQ + q0 + 4*lg + r)*DIM + ln;
            #pragma unroll
            for (int tt = 0; tt < 8; ++tt) orow[tt*16] = acc[tt][r] * lr[r];
        }
    }
}

extern "C" void kernel_launch(void* const* d_in, const int* in_sizes, int n_in,
                              void* d_out, int out_size, void* d_ws, size_t ws_size,
                              hipStream_t stream) {
    const float* Q  = (const float*)d_in[0];
    const float* K  = (const float*)d_in[1];
    const float* V  = (const float*)d_in[2];
    const int*   VL = (const int*)d_in[3];
    float* O = (float*)d_out;

    const size_t elems = (size_t)16 * 2048 * 128;      // per-tensor element count
    _Float16* Kh = (_Float16*)d_ws;
    _Float16* Vt = Kh + elems;

    if (ws_size >= elems * 2 * sizeof(_Float16)) {     // deterministic: depends only on ws_size
        cvtK_kernel<<<dim3(2048), dim3(256), 0, stream>>>(K, Kh);
        cvtV_kernel<<<dim3(512),  dim3(256), 0, stream>>>(V, Vt);
        fa_kernel<true><<<dim3(512), dim3(256), 0, stream>>>(Q, K, V, Kh, Vt, VL, O);
    } else {
        fa_kernel<false><<<dim3(512), dim3(256), 0, stream>>>(Q, K, V, Kh, Vt, VL, O);
    }
}